// Round 1
// baseline (600.733 us; speedup 1.0000x reference)
//
#include <hip/hip_runtime.h>
#include <hip/hip_bf16.h>
#include <math.h>

#define BS 16
#define Q 1024
#define CC 92
#define T 128
#define M 1024   // columns in transposed problem (= Q)
#define NR 128   // rows in transposed problem (= T)

// ---------------------------------------------------------------------------
// Kernel 1: cost matrix. One wave per (b,q); 4 waves (256 thr) per block.
// Cb[b][q][t] = |px-tx|+|py-ty| - softmax(logits[b,q])[label[b,t]]
// ---------------------------------------------------------------------------
__global__ __launch_bounds__(256) void cost_kernel(
    const float* __restrict__ logits,   // [BS][Q][CC]
    const float* __restrict__ ppts,     // [BS][Q][2]
    const int*   __restrict__ tlab,     // [BS][T]
    const float* __restrict__ tpts,     // [BS][T][2]
    float* __restrict__ Cb)             // [BS][Q][T]
{
    const int blk  = blockIdx.x;        // 0..4095
    const int b    = blk >> 8;          // 256 blocks per batch
    const int wave = threadIdx.x >> 6;
    const int lane = threadIdx.x & 63;
    const int q    = (blk & 255) * 4 + wave;

    __shared__ float tx_sh[T], ty_sh[T];
    __shared__ int   lab_sh[T];
    __shared__ float logit_sh[4][CC];

    if (threadIdx.x < T) {
        lab_sh[threadIdx.x] = tlab[b * T + threadIdx.x];
        tx_sh[threadIdx.x]  = tpts[(b * T + threadIdx.x) * 2 + 0];
        ty_sh[threadIdx.x]  = tpts[(b * T + threadIdx.x) * 2 + 1];
    }

    const float* lrow = logits + ((size_t)b * Q + q) * CC;
    float l0 = lrow[lane];                                   // lane < 64 < 92
    float l1 = (lane + 64 < CC) ? lrow[lane + 64] : -INFINITY;
    logit_sh[wave][lane] = l0;
    if (lane + 64 < CC) logit_sh[wave][lane + 64] = l1;

    // wave max
    float mx = fmaxf(l0, l1);
    #pragma unroll
    for (int off = 32; off > 0; off >>= 1) mx = fmaxf(mx, __shfl_down(mx, off));
    mx = __shfl(mx, 0);
    // wave sum of exp
    float es = expf(l0 - mx) + ((lane + 64 < CC) ? expf(l1 - mx) : 0.0f);
    #pragma unroll
    for (int off = 32; off > 0; off >>= 1) es += __shfl_down(es, off);
    es = __shfl(es, 0);
    const float inv = 1.0f / es;

    const float px = ppts[((size_t)b * Q + q) * 2 + 0];
    const float py = ppts[((size_t)b * Q + q) * 2 + 1];

    __syncthreads();

    float* outrow = Cb + ((size_t)b * Q + q) * T;
    #pragma unroll
    for (int t = lane; t < T; t += 64) {
        int   labv = lab_sh[t];
        float prob = expf(logit_sh[wave][labv] - mx) * inv;
        float cp   = fabsf(px - tx_sh[t]) + fabsf(py - ty_sh[t]);
        outrow[t]  = cp - prob;
    }
}

// ---------------------------------------------------------------------------
// Kernel 2: transpose Cb[b][q][t] -> CbT[b][t][q] (coalesced solver reads)
// ---------------------------------------------------------------------------
__global__ __launch_bounds__(256) void transpose_kernel(
    const float* __restrict__ Cb, float* __restrict__ CbT)
{
    __shared__ float tile[32][33];
    const int b  = blockIdx.z;
    const int tx = threadIdx.x & 31;
    const int ty = threadIdx.x >> 5;          // 0..7
    const int q0 = blockIdx.x * 32;           // gridDim.x = 32
    const int t0 = blockIdx.y * 32;           // gridDim.y = 4
    const float* src = Cb  + (size_t)b * Q * T;
    float*       dst = CbT + (size_t)b * T * Q;
    #pragma unroll
    for (int k = 0; k < 32; k += 8)
        tile[ty + k][tx] = src[(size_t)(q0 + ty + k) * T + t0 + tx];
    __syncthreads();
    #pragma unroll
    for (int k = 0; k < 32; k += 8)
        dst[(size_t)(t0 + ty + k) * Q + q0 + tx] = tile[tx][ty + k];
}

// ---------------------------------------------------------------------------
// Kernel 3: Jonker-Volgenant per batch, one block (256 threads) per batch.
// Replicates the reference fp64 op sequence exactly.
// ---------------------------------------------------------------------------
__global__ __launch_bounds__(256) void solve_kernel(
    const float* __restrict__ Cb,    // [BS][Q][T]  (fallback, strided reads)
    const float* __restrict__ CbT,   // [BS][T][Q]  (preferred, coalesced)
    float* __restrict__ out_rows,    // [BS][T]
    float* __restrict__ out_cols,    // [BS][T]
    int useT)
{
    const int b   = blockIdx.x;
    const int tid = threadIdx.x;

    __shared__ double v_sh[M + 1];
    __shared__ double minv_sh[M + 1];
    __shared__ double u_sh[NR + 1];
    __shared__ int    p_sh[M + 1];
    __shared__ int    way_sh[M + 1];
    __shared__ unsigned char used_sh[M + 1];
    __shared__ int    j0_sh, j1_sh, brk_sh;
    __shared__ double delta_sh;
    __shared__ double wave_val[4];
    __shared__ int    wave_idx[4];
    __shared__ int    ans_sh[NR];

    for (int j = tid; j <= M; j += 256) { v_sh[j] = 0.0; p_sh[j] = 0; }
    for (int i = tid; i <= NR; i += 256) u_sh[i] = 0.0;
    __syncthreads();

    const float* CbB  = Cb  + (size_t)b * Q * T;
    const float* CbTB = CbT + (size_t)b * T * Q;

    for (int i = 1; i <= NR; ++i) {
        if (tid == 0) { p_sh[0] = i; j0_sh = 0; }
        for (int j = tid; j <= M; j += 256) {
            minv_sh[j] = INFINITY; way_sh[j] = 0; used_sh[j] = 0;
        }
        __syncthreads();

        int iter = 0;
        while (true) {
            const int j0 = j0_sh;
            if (tid == 0) used_sh[j0] = 1;
            __syncthreads();

            const int    i0  = p_sh[j0];
            const double ui0 = u_sh[i0];
            const float* rowp = useT ? (CbTB + (size_t)(i0 - 1) * Q)
                                     : (CbB + (i0 - 1));

            double bestv = INFINITY; int bestj = 1;
            #pragma unroll
            for (int k = 0; k < 4; ++k) {
                const int j = 1 + tid + k * 256;
                if (!used_sh[j]) {
                    float  c   = useT ? rowp[j - 1] : rowp[(size_t)(j - 1) * T];
                    double cur = (double)c - ui0 - v_sh[j];
                    double mv  = minv_sh[j];
                    if (cur < mv) { mv = cur; minv_sh[j] = cur; way_sh[j] = j0; }
                    if (mv < bestv || (mv == bestv && j < bestj)) { bestv = mv; bestj = j; }
                }
            }
            // wave argmin reduction (min value, then min index)
            #pragma unroll
            for (int off = 32; off > 0; off >>= 1) {
                double ov = __shfl_down(bestv, off);
                int    oj = __shfl_down(bestj, off);
                if (ov < bestv || (ov == bestv && oj < bestj)) { bestv = ov; bestj = oj; }
            }
            const int wv = tid >> 6;
            if ((tid & 63) == 0) { wave_val[wv] = bestv; wave_idx[wv] = bestj; }
            __syncthreads();
            if (tid == 0) {
                double bv = wave_val[0]; int bj = wave_idx[0];
                #pragma unroll
                for (int w = 1; w < 4; ++w) {
                    if (wave_val[w] < bv || (wave_val[w] == bv && wave_idx[w] < bj)) {
                        bv = wave_val[w]; bj = wave_idx[w];
                    }
                }
                delta_sh = bv; j1_sh = bj;
            }
            __syncthreads();
            const double delta = delta_sh;
            const int    j1    = j1_sh;

            // u[p[used]] += delta; v[used] -= delta; minv[free] -= delta
            for (int j = tid; j <= M; j += 256) {
                if (used_sh[j]) { u_sh[p_sh[j]] += delta; v_sh[j] -= delta; }
                else if (j >= 1) minv_sh[j] -= delta;
            }
            __syncthreads();
            if (tid == 0) { j0_sh = j1; brk_sh = (p_sh[j1] == 0); }
            __syncthreads();
            if (brk_sh) break;
            if (++iter > M + 2) break;   // safety: never hang
        }

        if (tid == 0) {   // augment
            int j0 = j0_sh;
            while (j0 != 0) {
                int j1 = way_sh[j0];
                p_sh[j0] = p_sh[j1];
                j0 = j1;
            }
        }
        __syncthreads();
    }

    // ans[t] = matched q
    for (int j = 1 + tid; j <= M; j += 256) {
        int pj = p_sh[j];
        if (pj > 0) ans_sh[pj - 1] = j - 1;
    }
    __syncthreads();
    // argsort by q (all distinct): rank each t, scatter
    for (int t = tid; t < NR; t += 256) {
        int q = ans_sh[t];
        int rank = 0;
        for (int t2 = 0; t2 < NR; ++t2) rank += (ans_sh[t2] < q);
        out_rows[b * NR + rank] = (float)q;
        out_cols[b * NR + rank] = (float)t;
    }
}

// ---------------------------------------------------------------------------
extern "C" void kernel_launch(void* const* d_in, const int* in_sizes, int n_in,
                              void* d_out, int out_size, void* d_ws, size_t ws_size,
                              hipStream_t stream) {
    const float* logits = (const float*)d_in[0];
    const float* ppts   = (const float*)d_in[1];
    const int*   tlab   = (const int*)  d_in[2];
    const float* tpts   = (const float*)d_in[3];

    float* Cb   = (float*)d_out;                 // BS*Q*T floats
    float* rows = Cb + (size_t)BS * Q * T;       // BS*T floats
    float* cols = rows + (size_t)BS * T;         // BS*T floats
    float* CbT  = (float*)d_ws;

    const size_t cbt_bytes = (size_t)BS * Q * T * sizeof(float);   // 8 MiB
    const int useT = (ws_size >= cbt_bytes) ? 1 : 0;

    cost_kernel<<<4096, 256, 0, stream>>>(logits, ppts, tlab, tpts, Cb);
    if (useT)
        transpose_kernel<<<dim3(32, 4, BS), 256, 0, stream>>>(Cb, CbT);
    solve_kernel<<<BS, 256, 0, stream>>>(Cb, CbT, rows, cols, useT);
}

// Round 2
// 409.911 us; speedup vs baseline: 1.4655x; 1.4655x over previous
//
#include <hip/hip_runtime.h>
#include <hip/hip_bf16.h>
#include <math.h>

#define BS 16
#define Q 1024
#define CC 92
#define T 128
#define M 1024   // columns in transposed problem (= Q)
#define NR 128   // rows in transposed problem (= T)

// ---------------------------------------------------------------------------
// Kernel 1: cost matrix. One wave per (b,q); 4 waves (256 thr) per block.
// Cb[b][q][t] = |px-tx|+|py-ty| - softmax(logits[b,q])[label[b,t]]
// (unchanged from R1 — passed with absmax 0.0)
// ---------------------------------------------------------------------------
__global__ __launch_bounds__(256) void cost_kernel(
    const float* __restrict__ logits,   // [BS][Q][CC]
    const float* __restrict__ ppts,     // [BS][Q][2]
    const int*   __restrict__ tlab,     // [BS][T]
    const float* __restrict__ tpts,     // [BS][T][2]
    float* __restrict__ Cb)             // [BS][Q][T]
{
    const int blk  = blockIdx.x;        // 0..4095
    const int b    = blk >> 8;          // 256 blocks per batch
    const int wave = threadIdx.x >> 6;
    const int lane = threadIdx.x & 63;
    const int q    = (blk & 255) * 4 + wave;

    __shared__ float tx_sh[T], ty_sh[T];
    __shared__ int   lab_sh[T];
    __shared__ float logit_sh[4][CC];

    if (threadIdx.x < T) {
        lab_sh[threadIdx.x] = tlab[b * T + threadIdx.x];
        tx_sh[threadIdx.x]  = tpts[(b * T + threadIdx.x) * 2 + 0];
        ty_sh[threadIdx.x]  = tpts[(b * T + threadIdx.x) * 2 + 1];
    }

    const float* lrow = logits + ((size_t)b * Q + q) * CC;
    float l0 = lrow[lane];                                   // lane < 64 < 92
    float l1 = (lane + 64 < CC) ? lrow[lane + 64] : -INFINITY;
    logit_sh[wave][lane] = l0;
    if (lane + 64 < CC) logit_sh[wave][lane + 64] = l1;

    // wave max
    float mx = fmaxf(l0, l1);
    #pragma unroll
    for (int off = 32; off > 0; off >>= 1) mx = fmaxf(mx, __shfl_down(mx, off));
    mx = __shfl(mx, 0);
    // wave sum of exp
    float es = expf(l0 - mx) + ((lane + 64 < CC) ? expf(l1 - mx) : 0.0f);
    #pragma unroll
    for (int off = 32; off > 0; off >>= 1) es += __shfl_down(es, off);
    es = __shfl(es, 0);
    const float inv = 1.0f / es;

    const float px = ppts[((size_t)b * Q + q) * 2 + 0];
    const float py = ppts[((size_t)b * Q + q) * 2 + 1];

    __syncthreads();

    float* outrow = Cb + ((size_t)b * Q + q) * T;
    #pragma unroll
    for (int t = lane; t < T; t += 64) {
        int   labv = lab_sh[t];
        float prob = expf(logit_sh[wave][labv] - mx) * inv;
        float cp   = fabsf(px - tx_sh[t]) + fabsf(py - ty_sh[t]);
        outrow[t]  = cp - prob;
    }
}

// ---------------------------------------------------------------------------
// Kernel 2: transpose Cb[b][q][t] -> CbT[b][t][q]  (unchanged)
// ---------------------------------------------------------------------------
__global__ __launch_bounds__(256) void transpose_kernel(
    const float* __restrict__ Cb, float* __restrict__ CbT)
{
    __shared__ float tile[32][33];
    const int b  = blockIdx.z;
    const int tx = threadIdx.x & 31;
    const int ty = threadIdx.x >> 5;          // 0..7
    const int q0 = blockIdx.x * 32;           // gridDim.x = 32
    const int t0 = blockIdx.y * 32;           // gridDim.y = 4
    const float* src = Cb  + (size_t)b * Q * T;
    float*       dst = CbT + (size_t)b * T * Q;
    #pragma unroll
    for (int k = 0; k < 32; k += 8)
        tile[ty + k][tx] = src[(size_t)(q0 + ty + k) * T + t0 + tx];
    __syncthreads();
    #pragma unroll
    for (int k = 0; k < 32; k += 8)
        dst[(size_t)(t0 + ty + k) * Q + q0 + tx] = tile[tx][ty + k];
}

// ---------------------------------------------------------------------------
// Kernel 3: JV solver, scipy/Crouse variant. ONE WAVE (64 threads) per batch.
// Per-column state in registers: lane L owns columns j = L + 64*k, k=0..15.
//   v_[k], dist_[k] : fp64 duals / shortest-path costs (registers)
//   used            : 16-bit SC mask (register)
// LDS: row4col[1024], col4row[128], u[128], path[1024], SR record.
// No __syncthreads in the search loop (single wave, lockstep).
// ---------------------------------------------------------------------------
template<int USET>
__global__ __launch_bounds__(64) void solve_kernel(
    const float* __restrict__ Cb,    // [BS][Q][T] fallback (strided)
    const float* __restrict__ CbT,   // [BS][T][Q] row-major solver cost
    float* __restrict__ out_rows,    // [BS][T]
    float* __restrict__ out_cols)    // [BS][T]
{
    const int b    = blockIdx.x;
    const int lane = threadIdx.x;    // 0..63

    __shared__ int    row4col[M];    // col j -> row (-1 free)
    __shared__ int    col4row[NR];   // row i -> col (-1 free)
    __shared__ double u_sh[NR];
    __shared__ int    path_lds[M];   // predecessor row for col j
    __shared__ int    SRr[NR];       // rows that joined SR (excl. curRow)
    __shared__ double SRd[NR];       // dist at which they joined

    const float* CbB  = Cb  + (size_t)b * Q * T;
    const float* CbTB = CbT + (size_t)b * T * Q;

    double v_[16], dist_[16];
    #pragma unroll
    for (int k = 0; k < 16; ++k) v_[k] = 0.0;
    for (int j = lane; j < M;  j += 64) row4col[j] = -1;
    for (int i = lane; i < NR; i += 64) { col4row[i] = -1; u_sh[i] = 0.0; }
    __syncthreads();

    const double DINF = (double)INFINITY;

    for (int curRow = 0; curRow < NR; ++curRow) {
        #pragma unroll
        for (int k = 0; k < 16; ++k) dist_[k] = DINF;
        unsigned used  = 0;          // SC bitmask, bit k = col lane+64k
        double   minVal = 0.0;
        int      i_s  = curRow;      // current tree row (uniform)
        int      sink = -1;
        int      cnt  = 0;           // SR entries (uniform shadow)

        for (int guard = 0; guard <= M; ++guard) {
            const double ui = u_sh[i_s];         // broadcast LDS read
            const double s  = minVal - ui;

            // load this row's 16 costs (coalesced: 64 lanes x 4B contiguous)
            float c[16];
            if (USET) {
                const float* row = CbTB + (size_t)i_s * Q;
                #pragma unroll
                for (int k = 0; k < 16; ++k) c[k] = row[lane + 64 * k];
            } else {
                const float* col = CbB + i_s;
                #pragma unroll
                for (int k = 0; k < 16; ++k) c[k] = col[(size_t)(lane + 64 * k) * T];
            }

            // relax free columns + per-lane argmin
            double lmin = DINF; int lidx = 0x7fffffff;
            #pragma unroll
            for (int k = 0; k < 16; ++k) {
                const bool fr = ((used >> k) & 1u) == 0u;
                double r = s + (double)c[k] - v_[k];
                if (fr && r < dist_[k]) {
                    dist_[k] = r;
                    path_lds[lane + 64 * k] = i_s;   // 2-way bank alias: free
                }
                double a = fr ? dist_[k] : DINF;
                int jj = lane + 64 * k;
                if (a < lmin) { lmin = a; lidx = jj; }
            }

            // wave argmin butterfly (value, then smaller index)
            double bv = lmin; int bj = lidx;
            #pragma unroll
            for (int off = 32; off > 0; off >>= 1) {
                double ov = __shfl_xor(bv, off);
                int    oj = __shfl_xor(bj, off);
                if (ov < bv || (ov == bv && oj < bj)) { bv = ov; bj = oj; }
            }
            minVal = bv;
            const int jstar = __builtin_amdgcn_readfirstlane(bj);

            if ((jstar & 63) == lane) used |= (1u << (jstar >> 6));

            const int ra = row4col[jstar];       // broadcast LDS read
            if (ra == -1) { sink = jstar; break; }
            if (lane == 0 && cnt < NR) { SRr[cnt] = ra; SRd[cnt] = bv; }
            cnt++;
            i_s = __builtin_amdgcn_readfirstlane(ra);
        }

        // dual updates (out-of-loop, scipy style)
        #pragma unroll
        for (int k = 0; k < 16; ++k)
            if ((used >> k) & 1u) v_[k] += dist_[k] - minVal;   // v -= minVal-dist

        if (lane == 0) u_sh[curRow] += minVal;
        for (int t = lane; t < cnt; t += 64)
            u_sh[SRr[t]] += minVal - SRd[t];     // distinct rows, no race

        // augment along path (serial, lane 0)
        if (lane == 0) {
            int j = sink;
            for (int g = 0; g < NR + 2; ++g) {
                int pi = path_lds[j];
                row4col[j] = pi;
                int jn = col4row[pi];
                col4row[pi] = j;
                if (pi == curRow) break;
                j = jn;
            }
        }
        __syncthreads();   // order lane-0 LDS writes before next augmentation
    }

    // outputs: transposed case -> row_idx = sorted q, col_idx = matching t
    for (int t = lane; t < NR; t += 64) {
        int q = col4row[t];
        int rank = 0;
        for (int t2 = 0; t2 < NR; ++t2) rank += (col4row[t2] < q);
        out_rows[b * NR + rank] = (float)q;
        out_cols[b * NR + rank] = (float)t;
    }
}

// ---------------------------------------------------------------------------
extern "C" void kernel_launch(void* const* d_in, const int* in_sizes, int n_in,
                              void* d_out, int out_size, void* d_ws, size_t ws_size,
                              hipStream_t stream) {
    const float* logits = (const float*)d_in[0];
    const float* ppts   = (const float*)d_in[1];
    const int*   tlab   = (const int*)  d_in[2];
    const float* tpts   = (const float*)d_in[3];

    float* Cb   = (float*)d_out;                 // BS*Q*T floats
    float* rows = Cb + (size_t)BS * Q * T;       // BS*T floats
    float* cols = rows + (size_t)BS * T;         // BS*T floats
    float* CbT  = (float*)d_ws;

    const size_t cbt_bytes = (size_t)BS * Q * T * sizeof(float);   // 8 MiB
    const int useT = (ws_size >= cbt_bytes) ? 1 : 0;

    cost_kernel<<<4096, 256, 0, stream>>>(logits, ppts, tlab, tpts, Cb);
    if (useT) {
        transpose_kernel<<<dim3(32, 4, BS), 256, 0, stream>>>(Cb, CbT);
        solve_kernel<1><<<BS, 64, 0, stream>>>(Cb, CbT, rows, cols);
    } else {
        solve_kernel<0><<<BS, 64, 0, stream>>>(Cb, CbT, rows, cols);
    }
}

// Round 3
// 319.015 us; speedup vs baseline: 1.8831x; 1.2849x over previous
//
#include <hip/hip_runtime.h>
#include <hip/hip_bf16.h>
#include <math.h>

#define BS 16
#define Q 1024
#define CC 92
#define T 128
#define M 1024   // columns in transposed problem (= Q)
#define NR 128   // rows in transposed problem (= T)

// ---------------------------------------------------------------------------
// Kernel 1: cost matrix. One wave per (b,q); 4 waves (256 thr) per block.
// (unchanged — passed with absmax 0.0)
// ---------------------------------------------------------------------------
__global__ __launch_bounds__(256) void cost_kernel(
    const float* __restrict__ logits,   // [BS][Q][CC]
    const float* __restrict__ ppts,     // [BS][Q][2]
    const int*   __restrict__ tlab,     // [BS][T]
    const float* __restrict__ tpts,     // [BS][T][2]
    float* __restrict__ Cb)             // [BS][Q][T]
{
    const int blk  = blockIdx.x;        // 0..4095
    const int b    = blk >> 8;          // 256 blocks per batch
    const int wave = threadIdx.x >> 6;
    const int lane = threadIdx.x & 63;
    const int q    = (blk & 255) * 4 + wave;

    __shared__ float tx_sh[T], ty_sh[T];
    __shared__ int   lab_sh[T];
    __shared__ float logit_sh[4][CC];

    if (threadIdx.x < T) {
        lab_sh[threadIdx.x] = tlab[b * T + threadIdx.x];
        tx_sh[threadIdx.x]  = tpts[(b * T + threadIdx.x) * 2 + 0];
        ty_sh[threadIdx.x]  = tpts[(b * T + threadIdx.x) * 2 + 1];
    }

    const float* lrow = logits + ((size_t)b * Q + q) * CC;
    float l0 = lrow[lane];                                   // lane < 64 < 92
    float l1 = (lane + 64 < CC) ? lrow[lane + 64] : -INFINITY;
    logit_sh[wave][lane] = l0;
    if (lane + 64 < CC) logit_sh[wave][lane + 64] = l1;

    float mx = fmaxf(l0, l1);
    #pragma unroll
    for (int off = 32; off > 0; off >>= 1) mx = fmaxf(mx, __shfl_down(mx, off));
    mx = __shfl(mx, 0);
    float es = expf(l0 - mx) + ((lane + 64 < CC) ? expf(l1 - mx) : 0.0f);
    #pragma unroll
    for (int off = 32; off > 0; off >>= 1) es += __shfl_down(es, off);
    es = __shfl(es, 0);
    const float inv = 1.0f / es;

    const float px = ppts[((size_t)b * Q + q) * 2 + 0];
    const float py = ppts[((size_t)b * Q + q) * 2 + 1];

    __syncthreads();

    float* outrow = Cb + ((size_t)b * Q + q) * T;
    #pragma unroll
    for (int t = lane; t < T; t += 64) {
        int   labv = lab_sh[t];
        float prob = expf(logit_sh[wave][labv] - mx) * inv;
        float cp   = fabsf(px - tx_sh[t]) + fabsf(py - ty_sh[t]);
        outrow[t]  = cp - prob;
    }
}

// ---------------------------------------------------------------------------
// Kernel 2: transpose Cb[b][q][t] -> CbT[b][t][q]  (unchanged)
// ---------------------------------------------------------------------------
__global__ __launch_bounds__(256) void transpose_kernel(
    const float* __restrict__ Cb, float* __restrict__ CbT)
{
    __shared__ float tile[32][33];
    const int b  = blockIdx.z;
    const int tx = threadIdx.x & 31;
    const int ty = threadIdx.x >> 5;          // 0..7
    const int q0 = blockIdx.x * 32;           // gridDim.x = 32
    const int t0 = blockIdx.y * 32;           // gridDim.y = 4
    const float* src = Cb  + (size_t)b * Q * T;
    float*       dst = CbT + (size_t)b * T * Q;
    #pragma unroll
    for (int k = 0; k < 32; k += 8)
        tile[ty + k][tx] = src[(size_t)(q0 + ty + k) * T + t0 + tx];
    __syncthreads();
    #pragma unroll
    for (int k = 0; k < 32; k += 8)
        dst[(size_t)(t0 + ty + k) * Q + q0 + tx] = tile[tx][ty + k];
}

// ---------------------------------------------------------------------------
// Kernel 3: JV solver with greedy column-reduction init. ONE WAVE per batch.
// Lane L owns columns j = 256*g + 4*L + e  (g=0..3, e=0..3, k = 4g+e).
// Phase 1: per-row fp32 argmin (exact), u[i]=rowmin, greedy first-come assign.
// Phase 2: fp64 shortest augmenting path (scipy variant) for leftover rows.
// ---------------------------------------------------------------------------
template<int USET>
__global__ __launch_bounds__(64) void solve_kernel(
    const float* __restrict__ Cb,    // [BS][Q][T] fallback (strided)
    const float* __restrict__ CbT,   // [BS][T][Q] row-major solver cost
    float* __restrict__ out_rows,    // [BS][T]
    float* __restrict__ out_cols)    // [BS][T]
{
    const int b    = blockIdx.x;
    const int lane = threadIdx.x;    // 0..63

    __shared__ int    row4col[M];    // col j -> row (-1 free)
    __shared__ int    col4row[NR];   // row i -> col (-1 free)
    __shared__ double u_sh[NR];
    __shared__ int    path_lds[M];   // predecessor row for col j
    __shared__ int    SRr[NR];       // rows that joined SR (excl. curRow)
    __shared__ double SRd[NR];       // dist at which they joined
    __shared__ int    minj_sh[NR];   // greedy: per-row argmin column

    const float* CbB  = Cb  + (size_t)b * Q * T;
    const float* CbTB = CbT + (size_t)b * T * Q;

    for (int j = lane; j < M;  j += 64) row4col[j] = -1;
    for (int i = lane; i < NR; i += 64) col4row[i] = -1;
    __syncthreads();

    const double DINF = (double)INFINITY;

    // ---------------- Phase 1: row minima (fp32 exact) + greedy assign ----
    {
        float4 bufA[4], bufB[4];
        const float4* r0 = (const float4*)CbTB;
        #pragma unroll
        for (int g = 0; g < 4; ++g) bufA[g] = r0[lane + 64 * g];

        for (int i = 0; i < NR; ++i) {
            float4* cur = (i & 1) ? bufB : bufA;
            float4* nxt = (i & 1) ? bufA : bufB;
            if (i + 1 < NR) {
                const float4* rn = (const float4*)(CbTB + (size_t)(i + 1) * Q);
                #pragma unroll
                for (int g = 0; g < 4; ++g) nxt[g] = rn[lane + 64 * g];
            }
            // per-lane min as sortable u64 key: (mono32(c) << 10) | j
            unsigned long long bk = ~0ull;
            #pragma unroll
            for (int g = 0; g < 4; ++g) {
                const float* cf = (const float*)&cur[g];
                #pragma unroll
                for (int e = 0; e < 4; ++e) {
                    unsigned bits = __float_as_uint(cf[e]);
                    unsigned mono = (bits & 0x80000000u) ? ~bits
                                                         : (bits | 0x80000000u);
                    const int j = 256 * g + 4 * lane + e;
                    unsigned long long key =
                        ((unsigned long long)mono << 10) | (unsigned)j;
                    bk = (key < bk) ? key : bk;
                }
            }
            #pragma unroll
            for (int off = 32; off > 0; off >>= 1) {
                unsigned long long ok = __shfl_xor(bk, off);
                bk = (ok < bk) ? ok : bk;
            }
            if (lane == 0) {
                minj_sh[i] = (int)(bk & 1023u);
                unsigned mono = (unsigned)(bk >> 10);
                unsigned bits = (mono & 0x80000000u) ? (mono ^ 0x80000000u)
                                                     : ~mono;
                u_sh[i] = (double)__uint_as_float(bits);
            }
        }
        __syncthreads();

        // greedy first-come-first-served: row i wins col j iff it is the
        // first row whose argmin is j. Parallel first-occurrence scan.
        for (int i = lane; i < NR; i += 64) {
            const int mj = minj_sh[i];
            int first = -1;
            for (int t2 = 0; t2 < NR; ++t2) {          // broadcast LDS reads
                if (first < 0 && minj_sh[t2] == mj) first = t2;
            }
            if (first == i) { col4row[i] = mj; row4col[mj] = i; }
        }
        __syncthreads();
    }

    // ---------------- Phase 2: Dijkstra for unassigned rows (fp64) --------
    double v_[16], dist_[16];
    #pragma unroll
    for (int k = 0; k < 16; ++k) v_[k] = 0.0;

    for (int curRow = 0; curRow < NR; ++curRow) {
        if (col4row[curRow] >= 0) continue;            // greedy got it

        #pragma unroll
        for (int k = 0; k < 16; ++k) dist_[k] = DINF;
        unsigned used  = 0;          // SC bitmask, bit k
        double   minVal = 0.0;
        int      i_s  = curRow;
        int      sink = -1;
        int      cnt  = 0;

        for (int guard = 0; guard <= M; ++guard) {
            const double ui = u_sh[i_s];
            const double s  = minVal - ui;

            float4 c4[4];
            if (USET) {
                const float4* row = (const float4*)(CbTB + (size_t)i_s * Q);
                #pragma unroll
                for (int g = 0; g < 4; ++g) c4[g] = row[lane + 64 * g];
            } else {
                const float* col = CbB + i_s;
                #pragma unroll
                for (int g = 0; g < 4; ++g) {
                    float* cf = (float*)&c4[g];
                    #pragma unroll
                    for (int e = 0; e < 4; ++e)
                        cf[e] = col[(size_t)(256 * g + 4 * lane + e) * T];
                }
            }

            double lmin = DINF; int lidx = 0x7fffffff;
            #pragma unroll
            for (int g = 0; g < 4; ++g) {
                const float* cf = (const float*)&c4[g];
                #pragma unroll
                for (int e = 0; e < 4; ++e) {
                    const int k = 4 * g + e;
                    const int j = 256 * g + 4 * lane + e;   // ascending in k
                    const bool fr = ((used >> k) & 1u) == 0u;
                    double r = s + (double)cf[e] - v_[k];
                    if (fr && r < dist_[k]) {
                        dist_[k] = r;
                        path_lds[j] = i_s;
                    }
                    double a = fr ? dist_[k] : DINF;
                    if (a < lmin) { lmin = a; lidx = j; }
                }
            }

            // wave argmin butterfly (value, then smaller index)
            double bv = lmin; int bj = lidx;
            #pragma unroll
            for (int off = 32; off > 0; off >>= 1) {
                double ov = __shfl_xor(bv, off);
                int    oj = __shfl_xor(bj, off);
                if (ov < bv || (ov == bv && oj < bj)) { bv = ov; bj = oj; }
            }
            minVal = bv;
            const int jstar = __builtin_amdgcn_readfirstlane(bj);

            if (((jstar & 255) >> 2) == lane)
                used |= (1u << ((((jstar >> 8) << 2)) | (jstar & 3)));

            const int ra = row4col[jstar];
            if (ra == -1) { sink = jstar; break; }
            if (lane == 0 && cnt < NR) { SRr[cnt] = ra; SRd[cnt] = bv; }
            cnt++;
            i_s = __builtin_amdgcn_readfirstlane(ra);
        }

        // dual updates (scipy style, out of loop)
        #pragma unroll
        for (int k = 0; k < 16; ++k)
            if ((used >> k) & 1u) v_[k] += dist_[k] - minVal;

        if (lane == 0) u_sh[curRow] += minVal;
        for (int t = lane; t < cnt; t += 64)
            u_sh[SRr[t]] += minVal - SRd[t];

        // augment along path (serial, lane 0)
        if (lane == 0) {
            int j = sink;
            for (int g2 = 0; g2 < NR + 2; ++g2) {
                int pi = path_lds[j];
                row4col[j] = pi;
                int jn = col4row[pi];
                col4row[pi] = j;
                if (pi == curRow) break;
                j = jn;
            }
        }
        __syncthreads();
    }

    // outputs: row_idx = sorted q, col_idx = matching t
    for (int t = lane; t < NR; t += 64) {
        int q = col4row[t];
        int rank = 0;
        for (int t2 = 0; t2 < NR; ++t2) rank += (col4row[t2] < q);
        out_rows[b * NR + rank] = (float)q;
        out_cols[b * NR + rank] = (float)t;
    }
}

// ---------------------------------------------------------------------------
extern "C" void kernel_launch(void* const* d_in, const int* in_sizes, int n_in,
                              void* d_out, int out_size, void* d_ws, size_t ws_size,
                              hipStream_t stream) {
    const float* logits = (const float*)d_in[0];
    const float* ppts   = (const float*)d_in[1];
    const int*   tlab   = (const int*)  d_in[2];
    const float* tpts   = (const float*)d_in[3];

    float* Cb   = (float*)d_out;                 // BS*Q*T floats
    float* rows = Cb + (size_t)BS * Q * T;       // BS*T floats
    float* cols = rows + (size_t)BS * T;         // BS*T floats
    float* CbT  = (float*)d_ws;

    const size_t cbt_bytes = (size_t)BS * Q * T * sizeof(float);   // 8 MiB
    const int useT = (ws_size >= cbt_bytes) ? 1 : 0;

    cost_kernel<<<4096, 256, 0, stream>>>(logits, ppts, tlab, tpts, Cb);
    if (useT) {
        transpose_kernel<<<dim3(32, 4, BS), 256, 0, stream>>>(Cb, CbT);
        solve_kernel<1><<<BS, 64, 0, stream>>>(Cb, CbT, rows, cols);
    } else {
        solve_kernel<0><<<BS, 64, 0, stream>>>(Cb, CbT, rows, cols);
    }
}

// Round 4
// 163.064 us; speedup vs baseline: 3.6840x; 1.9564x over previous
//
#include <hip/hip_runtime.h>
#include <hip/hip_bf16.h>
#include <math.h>

#define BS 16
#define Q 1024
#define CC 92
#define T 128
#define M 1024   // columns in transposed problem (= Q)
#define NR 128   // rows in transposed problem (= T)

// ---------------------------------------------------------------------------
// Kernel 1: cost matrix. One wave per (b,q); 4 waves (256 thr) per block.
// (unchanged — passed with absmax 0.0)
// ---------------------------------------------------------------------------
__global__ __launch_bounds__(256) void cost_kernel(
    const float* __restrict__ logits,   // [BS][Q][CC]
    const float* __restrict__ ppts,     // [BS][Q][2]
    const int*   __restrict__ tlab,     // [BS][T]
    const float* __restrict__ tpts,     // [BS][T][2]
    float* __restrict__ Cb)             // [BS][Q][T]
{
    const int blk  = blockIdx.x;        // 0..4095
    const int b    = blk >> 8;          // 256 blocks per batch
    const int wave = threadIdx.x >> 6;
    const int lane = threadIdx.x & 63;
    const int q    = (blk & 255) * 4 + wave;

    __shared__ float tx_sh[T], ty_sh[T];
    __shared__ int   lab_sh[T];
    __shared__ float logit_sh[4][CC];

    if (threadIdx.x < T) {
        lab_sh[threadIdx.x] = tlab[b * T + threadIdx.x];
        tx_sh[threadIdx.x]  = tpts[(b * T + threadIdx.x) * 2 + 0];
        ty_sh[threadIdx.x]  = tpts[(b * T + threadIdx.x) * 2 + 1];
    }

    const float* lrow = logits + ((size_t)b * Q + q) * CC;
    float l0 = lrow[lane];                                   // lane < 64 < 92
    float l1 = (lane + 64 < CC) ? lrow[lane + 64] : -INFINITY;
    logit_sh[wave][lane] = l0;
    if (lane + 64 < CC) logit_sh[wave][lane + 64] = l1;

    float mx = fmaxf(l0, l1);
    #pragma unroll
    for (int off = 32; off > 0; off >>= 1) mx = fmaxf(mx, __shfl_down(mx, off));
    mx = __shfl(mx, 0);
    float es = expf(l0 - mx) + ((lane + 64 < CC) ? expf(l1 - mx) : 0.0f);
    #pragma unroll
    for (int off = 32; off > 0; off >>= 1) es += __shfl_down(es, off);
    es = __shfl(es, 0);
    const float inv = 1.0f / es;

    const float px = ppts[((size_t)b * Q + q) * 2 + 0];
    const float py = ppts[((size_t)b * Q + q) * 2 + 1];

    __syncthreads();

    float* outrow = Cb + ((size_t)b * Q + q) * T;
    #pragma unroll
    for (int t = lane; t < T; t += 64) {
        int   labv = lab_sh[t];
        float prob = expf(logit_sh[wave][labv] - mx) * inv;
        float cp   = fabsf(px - tx_sh[t]) + fabsf(py - ty_sh[t]);
        outrow[t]  = cp - prob;
    }
}

// ---------------------------------------------------------------------------
// Kernel 2: transpose Cb[b][q][t] -> CbT[b][t][q]  (unchanged)
// ---------------------------------------------------------------------------
__global__ __launch_bounds__(256) void transpose_kernel(
    const float* __restrict__ Cb, float* __restrict__ CbT)
{
    __shared__ float tile[32][33];
    const int b  = blockIdx.z;
    const int tx = threadIdx.x & 31;
    const int ty = threadIdx.x >> 5;          // 0..7
    const int q0 = blockIdx.x * 32;           // gridDim.x = 32
    const int t0 = blockIdx.y * 32;           // gridDim.y = 4
    const float* src = Cb  + (size_t)b * Q * T;
    float*       dst = CbT + (size_t)b * T * Q;
    #pragma unroll
    for (int k = 0; k < 32; k += 8)
        tile[ty + k][tx] = src[(size_t)(q0 + ty + k) * T + t0 + tx];
    __syncthreads();
    #pragma unroll
    for (int k = 0; k < 32; k += 8)
        dst[(size_t)(t0 + ty + k) * Q + q0 + tx] = tile[tx][ty + k];
}

// ---------------------------------------------------------------------------
// Kernel 2.5: per-row argmin as sortable u64 key, one WAVE per (b,row).
// key = (monotone_u32(cost) << 10) | j  -> min key == (min cost, min j)
// Massively parallel: removes phase-1 from the solver's serial chain.
// ---------------------------------------------------------------------------
__global__ __launch_bounds__(256) void rowmin_kernel(
    const float* __restrict__ CbT,             // [BS][NR][Q]
    unsigned long long* __restrict__ keys)     // [BS*NR]
{
    const int wave = threadIdx.x >> 6;
    const int lane = threadIdx.x & 63;
    const int gidx = blockIdx.x * 4 + wave;    // 0 .. BS*NR-1
    const float4* row = (const float4*)(CbT + (size_t)gidx * Q);

    unsigned long long bk = ~0ull;
    #pragma unroll
    for (int g = 0; g < 4; ++g) {
        float4 c4 = row[lane + 64 * g];
        const float* cf = (const float*)&c4;
        #pragma unroll
        for (int e = 0; e < 4; ++e) {
            unsigned bits = __float_as_uint(cf[e]);
            unsigned mono = (bits & 0x80000000u) ? ~bits : (bits | 0x80000000u);
            const int j = 256 * g + 4 * lane + e;
            unsigned long long key =
                ((unsigned long long)mono << 10) | (unsigned)j;
            bk = (key < bk) ? key : bk;
        }
    }
    #pragma unroll
    for (int off = 32; off > 0; off >>= 1) {
        unsigned long long ok = __shfl_xor(bk, off);
        bk = (ok < bk) ? ok : bk;
    }
    if (lane == 0) keys[gidx] = bk;
}

// ---------------------------------------------------------------------------
// Kernel 3: JV solver. ONE WAVE per batch.
// Lane L owns columns j = 256*g + 4*L + e  (g=0..3, e=0..3, k = 4g+e).
// Greedy init from precomputed rowmin keys (u[i]=rowmin, v=0: feasible+tight),
// then fp64 shortest augmenting path (scipy variant) for leftover rows.
// path_lds uses swizzled addressing A(j)=256g+64e+L -> conflict-free writes.
// ---------------------------------------------------------------------------
template<int USET>
__global__ __launch_bounds__(64) void solve_kernel(
    const float* __restrict__ Cb,    // [BS][Q][T] fallback (strided)
    const float* __restrict__ CbT,   // [BS][NR][Q] row-major solver cost
    const unsigned long long* __restrict__ keys,  // [BS*NR] or nullptr
    float* __restrict__ out_rows,    // [BS][T]
    float* __restrict__ out_cols)    // [BS][T]
{
    const int b    = blockIdx.x;
    const int lane = threadIdx.x;    // 0..63

    __shared__ int    row4col[M];    // col j -> row (-1 free)
    __shared__ int    col4row[NR];   // row i -> col (-1 free)
    __shared__ double u_sh[NR];
    __shared__ int    path_lds[M];   // swizzled: A(j) = 256g + 64e + L
    __shared__ int    SRr[NR];       // rows that joined SR (excl. curRow)
    __shared__ double SRd[NR];       // dist at which they joined
    __shared__ int    minj_sh[NR];   // greedy: per-row argmin column

    const float* CbB  = Cb  + (size_t)b * Q * T;
    const float* CbTB = CbT + (size_t)b * NR * Q;

    for (int j = lane; j < M;  j += 64) row4col[j] = -1;
    for (int i = lane; i < NR; i += 64) col4row[i] = -1;

    // decode rowmin keys -> u duals + greedy argmin columns
    if (keys) {
        for (int i = lane; i < NR; i += 64) {
            unsigned long long k = keys[(size_t)b * NR + i];
            minj_sh[i] = (int)(k & 1023u);
            unsigned mono = (unsigned)(k >> 10);
            unsigned bits = (mono & 0x80000000u) ? (mono ^ 0x80000000u) : ~mono;
            u_sh[i] = (double)__uint_as_float(bits);
        }
    } else {
        for (int i = lane; i < NR; i += 64) { minj_sh[i] = -1; u_sh[i] = 0.0; }
    }
    __syncthreads();

    // greedy first-come-first-served: row i wins col j iff it is the first
    // row whose argmin is j (parallel first-occurrence, broadcast LDS reads)
    if (keys) {
        for (int i = lane; i < NR; i += 64) {
            const int mj = minj_sh[i];
            int first = -1;
            for (int t2 = 0; t2 < NR; ++t2)
                if (first < 0 && minj_sh[t2] == mj) first = t2;
            if (first == i) { col4row[i] = mj; row4col[mj] = i; }
        }
        __syncthreads();
    }

    const double DINF = (double)INFINITY;
    double v_[16], dist_[16];
    #pragma unroll
    for (int k = 0; k < 16; ++k) v_[k] = 0.0;

    for (int curRow = 0; curRow < NR; ++curRow) {
        if (col4row[curRow] >= 0) continue;            // greedy got it

        #pragma unroll
        for (int k = 0; k < 16; ++k) dist_[k] = DINF;
        unsigned used  = 0;          // SC bitmask, bit k
        double   minVal = 0.0;
        int      i_s  = curRow;
        int      sink = -1;
        int      cnt  = 0;

        for (int guard = 0; guard <= M; ++guard) {
            const double ui = u_sh[i_s];
            const double s  = minVal - ui;

            float4 c4[4];
            if (USET) {
                const float4* row = (const float4*)(CbTB + (size_t)i_s * Q);
                #pragma unroll
                for (int g = 0; g < 4; ++g) c4[g] = row[lane + 64 * g];
            } else {
                const float* col = CbB + i_s;
                #pragma unroll
                for (int g = 0; g < 4; ++g) {
                    float* cf = (float*)&c4[g];
                    #pragma unroll
                    for (int e = 0; e < 4; ++e)
                        cf[e] = col[(size_t)(256 * g + 4 * lane + e) * T];
                }
            }

            double lmin = DINF; int lidx = 0x7fffffff;
            #pragma unroll
            for (int g = 0; g < 4; ++g) {
                const float* cf = (const float*)&c4[g];
                #pragma unroll
                for (int e = 0; e < 4; ++e) {
                    const int k = 4 * g + e;
                    const int j = 256 * g + 4 * lane + e;   // ascending in k
                    const bool fr = ((used >> k) & 1u) == 0u;
                    double r = s + (double)cf[e] - v_[k];
                    if (fr && r < dist_[k]) {
                        dist_[k] = r;
                        path_lds[256 * g + 64 * e + lane] = i_s;  // swizzled
                    }
                    double a = fr ? dist_[k] : DINF;
                    if (a < lmin) { lmin = a; lidx = j; }
                }
            }

            // speculative owner lookup for this lane's candidate (hides the
            // dependent row4col LDS latency behind the butterfly)
            const int cand = row4col[(lidx < M) ? lidx : 0];

            // wave argmin butterfly (value, then smaller index)
            double bv = lmin; int bj = lidx;
            #pragma unroll
            for (int off = 32; off > 0; off >>= 1) {
                double ov = __shfl_xor(bv, off);
                int    oj = __shfl_xor(bj, off);
                if (ov < bv || (ov == bv && oj < bj)) { bv = ov; bj = oj; }
            }
            minVal = bv;
            const int jstar = __builtin_amdgcn_readfirstlane(bj);

            if (((jstar >> 2) & 63) == lane)
                used |= (1u << (((jstar >> 8) << 2) | (jstar & 3)));

            const int ra =
                __builtin_amdgcn_readfirstlane(__shfl(cand, (jstar >> 2) & 63));
            if (ra == -1) { sink = jstar; break; }
            if (lane == 0 && cnt < NR) { SRr[cnt] = ra; SRd[cnt] = bv; }
            cnt++;
            i_s = ra;
        }

        // dual updates (scipy style, out of loop)
        #pragma unroll
        for (int k = 0; k < 16; ++k)
            if ((used >> k) & 1u) v_[k] += dist_[k] - minVal;

        if (lane == 0) u_sh[curRow] += minVal;
        for (int t = lane; t < cnt; t += 64)
            u_sh[SRr[t]] += minVal - SRd[t];

        // augment along path (serial, lane 0)
        if (lane == 0) {
            int j = sink;
            for (int g2 = 0; g2 < NR + 2; ++g2) {
                int pi = path_lds[((j >> 8) << 8) | ((j & 3) << 6) |
                                  ((j >> 2) & 63)];
                row4col[j] = pi;
                int jn = col4row[pi];
                col4row[pi] = j;
                if (pi == curRow) break;
                j = jn;
            }
        }
        __syncthreads();
    }

    // outputs: row_idx = sorted q, col_idx = matching t
    for (int t = lane; t < NR; t += 64) {
        int q = col4row[t];
        int rank = 0;
        for (int t2 = 0; t2 < NR; ++t2) rank += (col4row[t2] < q);
        out_rows[b * NR + rank] = (float)q;
        out_cols[b * NR + rank] = (float)t;
    }
}

// ---------------------------------------------------------------------------
extern "C" void kernel_launch(void* const* d_in, const int* in_sizes, int n_in,
                              void* d_out, int out_size, void* d_ws, size_t ws_size,
                              hipStream_t stream) {
    const float* logits = (const float*)d_in[0];
    const float* ppts   = (const float*)d_in[1];
    const int*   tlab   = (const int*)  d_in[2];
    const float* tpts   = (const float*)d_in[3];

    float* Cb   = (float*)d_out;                 // BS*Q*T floats
    float* rows = Cb + (size_t)BS * Q * T;       // BS*T floats
    float* cols = rows + (size_t)BS * T;         // BS*T floats

    float* CbT = (float*)d_ws;                               // 8 MiB
    unsigned long long* keys =
        (unsigned long long*)((char*)d_ws + (size_t)BS * NR * Q * sizeof(float));

    const size_t need = (size_t)BS * NR * Q * sizeof(float)
                      + (size_t)BS * NR * sizeof(unsigned long long);
    const int useT = (ws_size >= need) ? 1 : 0;

    cost_kernel<<<4096, 256, 0, stream>>>(logits, ppts, tlab, tpts, Cb);
    if (useT) {
        transpose_kernel<<<dim3(32, 4, BS), 256, 0, stream>>>(Cb, CbT);
        rowmin_kernel<<<BS * NR / 4, 256, 0, stream>>>(CbT, keys);
        solve_kernel<1><<<BS, 64, 0, stream>>>(Cb, CbT, keys, rows, cols);
    } else {
        solve_kernel<0><<<BS, 64, 0, stream>>>(Cb, CbT, nullptr, rows, cols);
    }
}